// Round 10
// baseline (173.559 us; speedup 1.0000x reference)
//
#include <hip/hip_runtime.h>
#include <stdint.h>

typedef __attribute__((ext_vector_type(8))) short bf16x8;
typedef __attribute__((ext_vector_type(4))) float f32x4;
typedef __attribute__((ext_vector_type(4))) unsigned int u32x4;

#define MFMA16(a, b, c) __builtin_amdgcn_mfma_f32_16x16x32_bf16(a, b, c, 0, 0, 0)

__device__ __forceinline__ float bf2f(unsigned short u) {
    union { unsigned int i; float f; } x; x.i = ((unsigned int)u) << 16; return x.f;
}
__device__ __forceinline__ unsigned short f2bf(float f) {
    union { float f; unsigned int i; } x; x.f = f;
    unsigned int u = x.i;
    return (unsigned short)((u + 0x7FFFu + ((u >> 16) & 1u)) >> 16);
}

// ---------------- P1: hs f32 -> A fragment-tiled bf16 ----------------
// At layout: tile t = mt*16 + kb (mt = m/16, kb = k/32), 512 bf16/tile:
// lane l, elem e -> A[m = mt*16 + (l&15)][k = kb*32 + (l>>4)*8 + e].
__global__ __launch_bounds__(256) void k_cvt(const float4* __restrict__ in,
                                             unsigned short* __restrict__ At) {
    __shared__ unsigned short t[16 * 512];  // 16 rows x 512 k, chunk-XOR swizzled
    const int tid = threadIdx.x;
    const int blk = blockIdx.x;             // = mt, band of 16 rows
#pragma unroll
    for (int it = 0; it < 8; ++it) {
        int idx = it * 256 + tid;           // 0..2047 float4s
        int row = idx >> 7, col4 = idx & 127;
        float4 v = in[(size_t)(blk * 16 + row) * 128 + col4];
        ushort4 o;
        o.x = f2bf(v.x); o.y = f2bf(v.y); o.z = f2bf(v.z); o.w = f2bf(v.w);
        int addr = row * 512 + (((col4 >> 1) ^ (row & 7)) << 3) + ((col4 & 1) << 2);
        *(ushort4*)&t[addr] = o;
    }
    __syncthreads();
#pragma unroll
    for (int it = 0; it < 4; ++it) {
        int idx = it * 256 + tid;           // 0..1023 = 16 tiles x 64 lanes
        int kb = idx >> 6, l = idx & 63;
        int row = l & 15, l4 = l >> 4;
        int c = (kb * 4 + l4) ^ (row & 7);
        bf16x8 v = *(const bf16x8*)&t[row * 512 + c * 8];
        *(bf16x8*)(At + ((size_t)(blk * 16 + kb) << 9) + l * 8) = v;
    }
}

// ---------------- P2: W [k][n] f32 -> Wt2 fragment-tiled bf16 ----------------
__global__ __launch_bounds__(256) void k_wt(const float* __restrict__ W0,
                                            const float* __restrict__ W1,
                                            const float* __restrict__ W2,
                                            unsigned short* __restrict__ Wt2) {
    int tile = blockIdx.x * 4 + (threadIdx.x >> 6);   // 0..1535
    int l = threadIdx.x & 63;
    int nt = tile >> 4;          // 0..95
    int kb = tile & 15;          // 0..15
    int mat = nt >> 5;
    const float* __restrict__ Wm = (mat == 0) ? W0 : (mat == 1) ? W1 : W2;
    int np = (nt & 31) * 16 + (l & 15);
    int k0 = kb * 32 + (l >> 4) * 8;
    bf16x8 o;
#pragma unroll
    for (int e = 0; e < 8; ++e) o[e] = (short)f2bf(Wm[(size_t)(k0 + e) * 512 + np]);
    *(bf16x8*)(Wt2 + (size_t)tile * 512 + l * 8) = o;
}

// ---------------- P3: RoPE cos/sin interleaved table [256][16][2] ----------------
__global__ __launch_bounds__(256) void k_sc(float* __restrict__ cs2) {
    int s = threadIdx.x;
    for (int f = 0; f < 16; ++f) {
        float inv = powf(10000.0f, -(float)f / 16.0f);
        float a = (float)s * inv;
        cs2[(s * 16 + f) * 2 + 0] = cosf(a);
        cs2[(s * 16 + f) * 2 + 1] = sinf(a);
    }
}

// ---------------- G: QKV GEMM ----------------
// A via LDS (frag-tiled, dbuf 32KB, linear gload_lds + linear ds_read, 0 conflicts);
// B direct global->reg from frag-tiled Wt2, SINGLE buffer (32 VGPR), issued right
// after the top-drain SYNC so compute's vmcnt-wait covers only LOADB (STAGE issued
// after it, in-order vmcnt). (256,3): demand ~135 vs cap ~170 -> no spill
// (R4/R5 spilled at demand ~180; R8 attn at cap 128 -- keep the margin).
__global__ __launch_bounds__(256, 3) void k_gemm(
    const unsigned short* __restrict__ At,   // frag-tiled A [1024 mt][16 kb][512]
    const unsigned short* __restrict__ Bt,   // frag-tiled W [96 nt][16 kb][512]
    const float* __restrict__ bq, const float* __restrict__ bk, const float* __restrict__ bv,
    const float* __restrict__ cs2,
    unsigned short* __restrict__ Qo, unsigned short* __restrict__ Ko, unsigned short* __restrict__ Vo) {
    __shared__ unsigned short a_l[2][8192];  // 2 x 16KB = 8 m-subtiles x 2 kb x 1KB tiles
    const int tid = threadIdx.x;
    const int wave = tid >> 6, lane = tid & 63;
    const int l15 = lane & 15, l4 = lane >> 4;
    // XCD-chunked swizzle: 1536 blocks = 8 XCDs x 192 (16 m-tiles x 12 n-tiles, n fast)
    int bid = blockIdx.x;
    int swz = (bid & 7) * 192 + (bid >> 3);
    const int m0 = (swz / 12) * 128;
    const int n0 = (swz % 12) * 128;
    const int wm = (wave >> 1) * 64, wn = (wave & 1) * 64;
    const bool isV = (n0 >= 1024);

    f32x4 zero4 = {0.f, 0.f, 0.f, 0.f};
    f32x4 acc[4][4];
#pragma unroll
    for (int i = 0; i < 4; ++i)
#pragma unroll
        for (int j = 0; j < 4; ++j) acc[i][j] = zero4;

    // A staging: wave stages 4 of the 16 1KB tiles per K-step (ti = wave*4+c)
    const unsigned short* gA = At + (((size_t)(m0 >> 4)) << 13) + lane * 8;
    // B: fragment tiles for this wave's n-half (nt = (n0+wn)/16 + j)
    const unsigned short* gB = Bt + (((size_t)((n0 + wn) >> 4)) << 13) + lane * 8;

#define STAGE(buf, kt)                                                                          \
    {                                                                                           \
        _Pragma("unroll")                                                                       \
        for (int c = 0; c < 4; ++c) {                                                           \
            int ti = wave * 4 + c;                                                              \
            int mi = ti >> 1, kbi = ti & 1;                                                     \
            __builtin_amdgcn_global_load_lds(                                                   \
                (const __attribute__((address_space(1))) unsigned int*)                         \
                    (gA + ((size_t)mi << 13) + ((kt) * 2 + kbi) * 512),                         \
                (__attribute__((address_space(3))) unsigned int*)(&a_l[(buf)][ti * 512]),       \
                16, 0, 0);                                                                      \
        }                                                                                       \
    }
#define LOADB(breg, kt)                                                                         \
    {                                                                                           \
        _Pragma("unroll")                                                                       \
        for (int kc = 0; kc < 2; ++kc)                                                          \
            _Pragma("unroll")                                                                   \
            for (int j = 0; j < 4; ++j)                                                         \
                breg[kc][j] = *(const bf16x8*)(gB + (size_t)j * 8192 + ((kt) * 2 + kc) * 512);  \
    }
#define COMPUTE(buf, breg)                                                                      \
    {                                                                                           \
        _Pragma("unroll")                                                                       \
        for (int kc = 0; kc < 2; ++kc) {                                                        \
            bf16x8 af[4];                                                                       \
            _Pragma("unroll")                                                                   \
            for (int i = 0; i < 4; ++i)                                                         \
                af[i] = *(const bf16x8*)&a_l[(buf)][((((wave >> 1) * 4 + i) << 1) + kc) * 512 + lane * 8]; \
            if (!isV) {                                                                         \
                _Pragma("unroll")                                                               \
                for (int i = 0; i < 4; ++i)                                                     \
                    _Pragma("unroll")                                                           \
                    for (int j = 0; j < 4; ++j)                                                 \
                        acc[i][j] = MFMA16(af[i], breg[kc][j], acc[i][j]);                      \
            } else {                                                                            \
                _Pragma("unroll")                                                               \
                for (int i = 0; i < 4; ++i)                                                     \
                    _Pragma("unroll")                                                           \
                    for (int j = 0; j < 4; ++j)                                                 \
                        acc[i][j] = MFMA16(breg[kc][j], af[i], acc[i][j]);                      \
            }                                                                                   \
        }                                                                                       \
    }
#define SYNC() { asm volatile("s_waitcnt vmcnt(0) lgkmcnt(0)" ::: "memory");                    \
                 __builtin_amdgcn_s_barrier(); }

    bf16x8 b[2][4];
    STAGE(0, 0);
    for (int kt = 0; kt < 8; ++kt) {
        SYNC();                            // prev STAGE landed (full compute phase of overlap)
        const int cur = kt & 1;
        LOADB(b, kt);                      // compute's vmcnt-wait covers only these 8 loads
        if (kt < 7) STAGE(cur ^ 1, kt + 1);
        COMPUTE(cur, b);
    }
#undef STAGE
#undef LOADB
#undef COMPUTE
#undef SYNC

    if (!isV) {
        const int mat = n0 >> 9;  // 0=Q, 1=K
        unsigned short* __restrict__ dst = (mat == 0) ? Qo : Ko;
        const float* __restrict__ bias = (mat == 0) ? bq : bk;
#pragma unroll
        for (int j = 0; j < 4; ++j) {
            int col = (n0 & 511) + wn + j * 16 + l15;  // 0..511
            float bb = bias[col];
            int h = col >> 5, dh = col & 31, f = dh >> 1;
            float sgn = (col & 1) ? 1.0f : -1.0f;
#pragma unroll
            for (int i = 0; i < 4; ++i) {
#pragma unroll
                for (int r = 0; r < 4; ++r) {
                    int m = m0 + wm + i * 16 + l4 * 4 + r;
                    int b2 = m >> 8, s = m & 255;
                    float t = acc[i][j][r] + bb;
                    float partner = __shfl_xor(t, 1);
                    float2 cn = *(const float2*)(cs2 + (s * 16 + f) * 2);
                    float o = t * cn.x + sgn * partner * cn.y;
                    dst[(size_t)(b2 * 16 + h) * 8192 + s * 32 + dh] = f2bf(o);
                }
            }
        }
    } else {
        // V: acc[i][j] = D[n_local = wn+j*16+l4*4+r][m_local = wm+i*16+l15]
#pragma unroll
        for (int j = 0; j < 4; ++j) {
#pragma unroll
            for (int r = 0; r < 4; ++r) {
                int n = (n0 & 511) + wn + j * 16 + l4 * 4 + r;  // 0..511
                float bb = bv[n];
                int h = n >> 5, dh = n & 31;
#pragma unroll
                for (int i = 0; i < 4; ++i) {
                    int m = m0 + wm + i * 16 + l15;
                    int b2 = m >> 8, s = m & 255;
                    Vo[(size_t)(b2 * 16 + h) * 8192 + dh * 256 + s] = f2bf(acc[i][j][r] + bb);
                }
            }
        }
    }
}

// ---------------- A: attention, in-register P ----------------
// (256,3): cap ~170 regs vs demand ~137 -> no spill. Q-frags for all 4 qb
// hoisted above the loop (latency exposed once, not 4x).
__global__ __launch_bounds__(256, 3) void k_attn(
    const unsigned short* __restrict__ Qm, const unsigned short* __restrict__ Km,
    const unsigned short* __restrict__ Vm,  // Vm is [b][h][dh][s]
    const float* __restrict__ bias_table, float* __restrict__ out) {
    __shared__ unsigned short k_l[256 * 32];   // linear [s][dh], conflict-free (4-chunk rows)
    __shared__ unsigned short vt_l[32 * 256];  // linear [dh][s], chunk-XOR swizzled content
    __shared__ float bias_g[512];              // rel-bias slice, all 4 q0 offsets (0..510)

    const int tid = threadIdx.x, wave = tid >> 6, lane = tid & 63;
    const int l15 = lane & 15, l4 = lane >> 4;
    // 1024 blocks = 8 XCDs x 128
    int bid = blockIdx.x;
    int swz = (bid & 7) * 128 + (bid >> 3);
    const int h = swz & 15, b = swz >> 4;
    const size_t bh = ((size_t)(b * 16 + h)) * 8192;

    for (int i = tid; i < 511; i += 256) bias_g[i] = bias_table[i * 16 + h];

    // K stage: straight 16KB copy via global_load_lds
#pragma unroll
    for (int it = 0; it < 4; ++it) {
        int p = it * 256 + wave * 64 + lane;  // 16B chunk index
        __builtin_amdgcn_global_load_lds(
            (const __attribute__((address_space(1))) unsigned int*)(Km + bh + p * 8),
            (__attribute__((address_space(3))) unsigned int*)(k_l + it * 2048 + wave * 512), 16, 0, 0);
    }
    // V stage: source pre-swizzled (chunk c at lds pos c^(dh&7))
#pragma unroll
    for (int it = 0; it < 4; ++it) {
        int p = it * 256 + wave * 64 + lane;
        int dh = p >> 5, cpos = p & 31;
        int srcc = cpos ^ (dh & 7);
        __builtin_amdgcn_global_load_lds(
            (const __attribute__((address_space(1))) unsigned int*)(Vm + bh + dh * 256 + srcc * 8),
            (__attribute__((address_space(3))) unsigned int*)(vt_l + it * 2048 + wave * 512), 16, 0, 0);
    }

    const int qrow = 16 * wave + l15;
    // Q fragments for all 4 q-blocks, hoisted (independent loads, latency paid once)
    bf16x8 qf[4];
#pragma unroll
    for (int qb = 0; qb < 4; ++qb)
        qf[qb] = *(const bf16x8*)(Qm + bh + (size_t)(qb * 64 + qrow) * 32 + l4 * 8);
    __syncthreads();
    // k_l / vt_l / bias_g read-only from here -> no more barriers.

    f32x4 zero4 = {0.f, 0.f, 0.f, 0.f};
    const float SCL2 = 0.17677669529663687f * 1.4426950408889634f;
    const bool hi = (l4 >> 1) != 0;   // a
    const bool odd = (l4 & 1) != 0;   // b

#pragma unroll 1
    for (int qb = 0; qb < 4; ++qb) {
        const int q0 = qb * 64;
        bf16x8 qfrag = qf[qb];

        // QK^T swapped: sc[ct] holds scores(k = 16ct+4*l4+r, q = q0+16w+l15)
        f32x4 sc[16];
#pragma unroll
        for (int ct = 0; ct < 16; ++ct) {
            bf16x8 kf = *(const bf16x8*)&k_l[(ct * 16 + l15) * 32 + l4 * 8];
            sc[ct] = MFMA16(kf, qfrag, zero4);
        }

        // softmax (no max-subtraction: scores ~N(0,1) after scale, exp arg bounded)
        float sum = 0.f;
#pragma unroll
        for (int ct = 0; ct < 16; ++ct) {
#pragma unroll
            for (int r = 0; r < 4; ++r) {
                float e;
                float x = sc[ct][r] * SCL2;
                asm("v_exp_f32 %0, %1" : "=v"(e) : "v"(x));
                sc[ct][r] = e;
                sum += e;
            }
        }
        sum += __shfl_xor(sum, 16);
        sum += __shfl_xor(sum, 32);
        float inv = 1.0f / sum;

        // PV with in-register P-redistribution (acc layout -> A-frag layout)
        f32x4 o0 = zero4, o1 = zero4;
#pragma unroll
        for (int m = 0; m < 8; ++m) {
            unsigned int E0, E1, O0, O1;
            {
                int kbase = 32 * m + 4 * l4;
                int jb = q0 + qrow - kbase + 255;
                float p0 = sc[2 * m][0] * inv + bias_g[jb];
                float p1 = sc[2 * m][1] * inv + bias_g[jb - 1];
                float p2 = sc[2 * m][2] * inv + bias_g[jb - 2];
                float p3 = sc[2 * m][3] * inv + bias_g[jb - 3];
                asm("v_cvt_pk_bf16_f32 %0, %1, %2" : "=v"(E0) : "v"(p0), "v"(p1));
                asm("v_cvt_pk_bf16_f32 %0, %1, %2" : "=v"(E1) : "v"(p2), "v"(p3));
                jb -= 16;
                p0 = sc[2 * m + 1][0] * inv + bias_g[jb];
                p1 = sc[2 * m + 1][1] * inv + bias_g[jb - 1];
                p2 = sc[2 * m + 1][2] * inv + bias_g[jb - 2];
                p3 = sc[2 * m + 1][3] * inv + bias_g[jb - 3];
                asm("v_cvt_pk_bf16_f32 %0, %1, %2" : "=v"(O0) : "v"(p0), "v"(p1));
                asm("v_cvt_pk_bf16_f32 %0, %1, %2" : "=v"(O1) : "v"(p2), "v"(p3));
            }
            unsigned int m0_ = hi ? O0 : E0, m1_ = hi ? O1 : E1;  // own parity-a pair
            unsigned int s0 = hi ? E0 : O0, s1 = hi ? E1 : O1;    // give-away pair
            unsigned int g0 = __shfl_xor(s0, 32), g1 = __shfl_xor(s1, 32);
            unsigned int X00 = hi ? g0 : m0_, X01 = hi ? g1 : m1_;  // (a'=0, b'=b)
            unsigned int X10 = hi ? m0_ : g0, X11 = hi ? m1_ : g1;  // (a'=1, b'=b)
            unsigned int k0 = odd ? X10 : X00, k1 = odd ? X11 : X01;  // keep (a'=b)
            unsigned int t0 = odd ? X00 : X10, t1 = odd ? X01 : X11;  // send (a'=1-b)
            unsigned int r0 = __shfl_xor(t0, 16), r1 = __shfl_xor(t1, 16);
            union { unsigned int u[4]; bf16x8 v; } pu;
            pu.u[0] = odd ? r0 : k0; pu.u[1] = odd ? r1 : k1;   // b'=0 source
            pu.u[2] = odd ? k0 : r0; pu.u[3] = odd ? k1 : r1;   // b'=1 source
            int vc = (m * 4 + l4) ^ (l15 & 7);
            bf16x8 v0 = *(const bf16x8*)&vt_l[l15 * 256 + vc * 8];
            bf16x8 v1 = *(const bf16x8*)&vt_l[(16 + l15) * 256 + vc * 8];
            o0 = MFMA16(pu.v, v0, o0);
            o1 = MFMA16(pu.v, v1, o1);
        }

        // write out[b][s][h*32+dh] f32
#pragma unroll
        for (int r = 0; r < 4; ++r) {
            int s = q0 + 16 * wave + l4 * 4 + r;
            float* po = out + ((size_t)(b * 256 + s)) * 512 + h * 32;
            po[l15] = o0[r];
            po[16 + l15] = o1[r];
        }
    }
}

// ---------------- launch ----------------
extern "C" void kernel_launch(void* const* d_in, const int* in_sizes, int n_in,
                              void* d_out, int out_size, void* d_ws, size_t ws_size,
                              hipStream_t stream) {
    const float* hs = (const float*)d_in[0];
    const float* Wq = (const float*)d_in[1];
    const float* bq = (const float*)d_in[2];
    const float* Wk = (const float*)d_in[3];
    const float* bk = (const float*)d_in[4];
    const float* Wv = (const float*)d_in[5];
    const float* bv = (const float*)d_in[6];
    const float* bt = (const float*)d_in[7];
    float* out = (float*)d_out;

    char* ws = (char*)d_ws;
    unsigned short* hsb = (unsigned short*)ws;                 // 16,777,216 B (frag-tiled A)
    unsigned short* wt = (unsigned short*)(ws + 16777216);     //  1,572,864 B (frag-tiled W)
    unsigned short* Qo = (unsigned short*)(ws + 18350080);     // 16,777,216 B
    unsigned short* Ko = (unsigned short*)(ws + 35127296);     // 16,777,216 B
    unsigned short* Vo = (unsigned short*)(ws + 51904512);     // 16,777,216 B ([b][h][dh][s])
    float* cs2 = (float*)(ws + 68681728);                      //     32,768 B

    hipLaunchKernelGGL(k_cvt, dim3(1024), dim3(256), 0, stream, (const float4*)hs, hsb);
    hipLaunchKernelGGL(k_wt, dim3(384), dim3(256), 0, stream, Wq, Wk, Wv, wt);
    hipLaunchKernelGGL(k_sc, dim3(1), dim3(256), 0, stream, cs2);
    hipLaunchKernelGGL(k_gemm, dim3(1536), dim3(256), 0, stream,
                       hsb, wt, bq, bk, bv, cs2, Qo, Ko, Vo);
    hipLaunchKernelGGL(k_attn, dim3(1024), dim3(256), 0, stream,
                       Qo, Ko, Vo, bt, out);
}

// Round 11
// 96.472 us; speedup vs baseline: 1.7991x; 1.7991x over previous
//
#include <hip/hip_runtime.h>
#include <stdint.h>

typedef __attribute__((ext_vector_type(8))) short bf16x8;
typedef __attribute__((ext_vector_type(4))) float f32x4;
typedef __attribute__((ext_vector_type(4))) unsigned int u32x4;

#define MFMA16(a, b, c) __builtin_amdgcn_mfma_f32_16x16x32_bf16(a, b, c, 0, 0, 0)

__device__ __forceinline__ float bf2f(unsigned short u) {
    union { unsigned int i; float f; } x; x.i = ((unsigned int)u) << 16; return x.f;
}
__device__ __forceinline__ unsigned short f2bf(float f) {
    union { float f; unsigned int i; } x; x.f = f;
    unsigned int u = x.i;
    return (unsigned short)((u + 0x7FFFu + ((u >> 16) & 1u)) >> 16);
}

// ---------------- P1: hs f32 -> bf16 (row-major, measured-best R3 version) ----------------
__global__ __launch_bounds__(256) void k_cvt(const float4* __restrict__ in,
                                             unsigned short* __restrict__ out) {
    int i = blockIdx.x * 256 + threadIdx.x;
    float4 v = in[i];
    ushort4 o;
    o.x = f2bf(v.x); o.y = f2bf(v.y); o.z = f2bf(v.z); o.w = f2bf(v.w);
    *(ushort4*)(out + (size_t)i * 4) = o;
}

// ---------------- P2: W [k][n] f32 -> Wt [n][k] bf16 (3 mats) ----------------
__global__ __launch_bounds__(256) void k_wt(const float* __restrict__ W0,
                                            const float* __restrict__ W1,
                                            const float* __restrict__ W2,
                                            unsigned short* __restrict__ Wt) {
    __shared__ float t[64][65];
    const float* Wm = (blockIdx.z == 0) ? W0 : (blockIdx.z == 1) ? W1 : W2;
    int k0 = blockIdx.x * 64, n0 = blockIdx.y * 64;
    for (int it = 0; it < 16; ++it) {
        int idx = threadIdx.x + it * 256;
        int r = idx >> 6, c = idx & 63;
        t[r][c] = Wm[(k0 + r) * 512 + n0 + c];
    }
    __syncthreads();
    unsigned short* dst = Wt + (size_t)blockIdx.z * 512 * 512;
    for (int it = 0; it < 16; ++it) {
        int idx = threadIdx.x + it * 256;
        int nr = idx >> 6, kc = idx & 63;
        dst[(n0 + nr) * 512 + k0 + kc] = f2bf(t[kc][nr]);
    }
}

// ---------------- P3: RoPE cos/sin interleaved table [256][16][2] ----------------
__global__ __launch_bounds__(256) void k_sc(float* __restrict__ cs2) {
    int s = threadIdx.x;
    for (int f = 0; f < 16; ++f) {
        float inv = powf(10000.0f, -(float)f / 16.0f);
        float a = (float)s * inv;
        cs2[(s * 16 + f) * 2 + 0] = cosf(a);
        cs2[(s * 16 + f) * 2 + 1] = sinf(a);
    }
}

// ---------------- G: QKV GEMM (R3 verbatim -- measured best 45.0 us) ----------------
// Dbuf LDS A+B (XOR both-sides swizzle, 0 conflicts), STAGE issued before compute,
// one __syncthreads per K-step. (256,2): no spill (R4/R5/R10: (256,3) spills).
__global__ __launch_bounds__(256, 2) void k_gemm(
    const unsigned short* __restrict__ A,   // hsb [16384][512] bf16
    const unsigned short* __restrict__ Bw,  // wt  [1536][512] bf16 ([n][k])
    const float* __restrict__ bq, const float* __restrict__ bk, const float* __restrict__ bv,
    const float* __restrict__ cs2,
    unsigned short* __restrict__ Qo, unsigned short* __restrict__ Ko, unsigned short* __restrict__ Vo) {
    __shared__ unsigned short a_l[2][8192];
    __shared__ unsigned short b_l[2][8192];
    const int tid = threadIdx.x;
    const int wave = tid >> 6, lane = tid & 63;
    const int l15 = lane & 15, l4 = lane >> 4;
    // XCD-chunked swizzle: 1536 blocks = 8 XCDs x 192 (16 m-tiles each, n fast)
    int bid = blockIdx.x;
    int swz = (bid & 7) * 192 + (bid >> 3);
    const int m0 = (swz / 12) * 128;
    const int n0 = (swz % 12) * 128;
    const int wm = (wave >> 1) * 64, wn = (wave & 1) * 64;
    const bool isV = (n0 >= 1024);

    f32x4 zero4 = {0.f, 0.f, 0.f, 0.f};
    f32x4 acc[4][4];
#pragma unroll
    for (int i = 0; i < 4; ++i)
#pragma unroll
        for (int j = 0; j < 4; ++j) acc[i][j] = zero4;

    // staging: thread t covers row (t>>3)+32*it, source k-chunk XOR-preswizzled
    const int srow = tid >> 3;
    const int skc = ((tid & 7) ^ (srow & 7)) * 8;
    const unsigned short* ga = A + (size_t)(m0 + srow) * 512 + skc;
    const unsigned short* gb = Bw + (size_t)(n0 + srow) * 512 + skc;

#define STAGE(buf, kt)                                                                          \
    {                                                                                           \
        const unsigned short* pa = ga + (kt) * 64;                                              \
        const unsigned short* pb = gb + (kt) * 64;                                              \
        unsigned short* la = &a_l[(buf)][wave * 512];                                           \
        unsigned short* lb = &b_l[(buf)][wave * 512];                                           \
        _Pragma("unroll")                                                                       \
        for (int it = 0; it < 4; ++it) {                                                        \
            __builtin_amdgcn_global_load_lds(                                                   \
                (const __attribute__((address_space(1))) unsigned int*)(pa + it * (32 * 512)),  \
                (__attribute__((address_space(3))) unsigned int*)(la + it * 2048), 16, 0, 0);   \
            __builtin_amdgcn_global_load_lds(                                                   \
                (const __attribute__((address_space(1))) unsigned int*)(pb + it * (32 * 512)),  \
                (__attribute__((address_space(3))) unsigned int*)(lb + it * 2048), 16, 0, 0);   \
        }                                                                                       \
    }

    STAGE(0, 0);
    __syncthreads();
    int cur = 0;
    for (int kt = 0; kt < 8; ++kt) {
        if (kt < 7) STAGE(cur ^ 1, kt + 1);   // issue next-tile loads BEFORE compute
#pragma unroll
        for (int kc = 0; kc < 2; ++kc) {
            bf16x8 af[4], bfr[4];
#pragma unroll
            for (int i = 0; i < 4; ++i) {
                int g = ((kc * 4 + l4) ^ (l15 & 7)) * 8;   // read-side XOR
                af[i] = *(const bf16x8*)&a_l[cur][(wm + i * 16 + l15) * 64 + g];
            }
#pragma unroll
            for (int j = 0; j < 4; ++j) {
                int g = ((kc * 4 + l4) ^ (l15 & 7)) * 8;
                bfr[j] = *(const bf16x8*)&b_l[cur][(wn + j * 16 + l15) * 64 + g];
            }
            if (!isV) {
#pragma unroll
                for (int i = 0; i < 4; ++i)
#pragma unroll
                    for (int j = 0; j < 4; ++j) acc[i][j] = MFMA16(af[i], bfr[j], acc[i][j]);
            } else {
                // swapped operands: D[n_local][m_local] -> transposed V output
#pragma unroll
                for (int i = 0; i < 4; ++i)
#pragma unroll
                    for (int j = 0; j < 4; ++j) acc[i][j] = MFMA16(bfr[j], af[i], acc[i][j]);
            }
        }
        __syncthreads();   // drains this iter's STAGE (hidden under 32 MFMAs) + LDS reads
        cur ^= 1;
    }
#undef STAGE

    if (!isV) {
        const int mat = n0 >> 9;  // 0=Q, 1=K
        unsigned short* __restrict__ dst = (mat == 0) ? Qo : Ko;
        const float* __restrict__ bias = (mat == 0) ? bq : bk;
#pragma unroll
        for (int j = 0; j < 4; ++j) {
            int col = (n0 & 511) + wn + j * 16 + l15;  // 0..511
            float bb = bias[col];
            int h = col >> 5, dh = col & 31, f = dh >> 1;
            float sgn = (col & 1) ? 1.0f : -1.0f;
#pragma unroll
            for (int i = 0; i < 4; ++i) {
#pragma unroll
                for (int r = 0; r < 4; ++r) {
                    int m = m0 + wm + i * 16 + l4 * 4 + r;
                    int b2 = m >> 8, s = m & 255;
                    float t = acc[i][j][r] + bb;
                    float partner = __shfl_xor(t, 1);
                    float2 cn = *(const float2*)(cs2 + (s * 16 + f) * 2);
                    float o = t * cn.x + sgn * partner * cn.y;
                    dst[(size_t)(b2 * 16 + h) * 8192 + s * 32 + dh] = f2bf(o);
                }
            }
        }
    } else {
        // V: acc[i][j] = D[n_local = wn+j*16+l4*4+r][m_local = wm+i*16+l15]
#pragma unroll
        for (int j = 0; j < 4; ++j) {
#pragma unroll
            for (int r = 0; r < 4; ++r) {
                int n = (n0 & 511) + wn + j * 16 + l4 * 4 + r;  // 0..511
                float bb = bv[n];
                int h = n >> 5, dh = n & 31;
#pragma unroll
                for (int i = 0; i < 4; ++i) {
                    int m = m0 + wm + i * 16 + l15;
                    int b2 = m >> 8, s = m & 255;
                    Vo[(size_t)(b2 * 16 + h) * 8192 + dh * 256 + s] = f2bf(acc[i][j][r] + bb);
                }
            }
        }
    }
}

// ---------------- A: attention (R9 verbatim -- in-register P, (256,3), no Q-hoist) ----------------
// (256,3): cap ~170 regs vs demand ~125 -> no spill (R8's (256,4)=128 spilled;
// R10's +12-reg Q-hoist also regressed -- keep the margin, no hoist).
__global__ __launch_bounds__(256, 3) void k_attn(
    const unsigned short* __restrict__ Qm, const unsigned short* __restrict__ Km,
    const unsigned short* __restrict__ Vm,  // Vm is [b][h][dh][s]
    const float* __restrict__ bias_table, float* __restrict__ out) {
    __shared__ unsigned short k_l[256 * 32];   // linear [s][dh], conflict-free (4-chunk rows)
    __shared__ unsigned short vt_l[32 * 256];  // linear [dh][s], chunk-XOR swizzled content
    __shared__ float bias_g[512];              // rel-bias slice, all 4 q0 offsets (0..510)

    const int tid = threadIdx.x, wave = tid >> 6, lane = tid & 63;
    const int l15 = lane & 15, l4 = lane >> 4;
    // 1024 blocks = 8 XCDs x 128
    int bid = blockIdx.x;
    int swz = (bid & 7) * 128 + (bid >> 3);
    const int h = swz & 15, b = swz >> 4;
    const size_t bh = ((size_t)(b * 16 + h)) * 8192;

    for (int i = tid; i < 511; i += 256) bias_g[i] = bias_table[i * 16 + h];

    // K stage: straight 16KB copy via global_load_lds
#pragma unroll
    for (int it = 0; it < 4; ++it) {
        int p = it * 256 + wave * 64 + lane;  // 16B chunk index
        __builtin_amdgcn_global_load_lds(
            (const __attribute__((address_space(1))) unsigned int*)(Km + bh + p * 8),
            (__attribute__((address_space(3))) unsigned int*)(k_l + it * 2048 + wave * 512), 16, 0, 0);
    }
    // V stage: source pre-swizzled (chunk c at lds pos c^(dh&7))
#pragma unroll
    for (int it = 0; it < 4; ++it) {
        int p = it * 256 + wave * 64 + lane;
        int dh = p >> 5, cpos = p & 31;
        int srcc = cpos ^ (dh & 7);
        __builtin_amdgcn_global_load_lds(
            (const __attribute__((address_space(1))) unsigned int*)(Vm + bh + dh * 256 + srcc * 8),
            (__attribute__((address_space(3))) unsigned int*)(vt_l + it * 2048 + wave * 512), 16, 0, 0);
    }
    __syncthreads();
    // k_l / vt_l / bias_g read-only from here -> no more barriers.

    f32x4 zero4 = {0.f, 0.f, 0.f, 0.f};
    const float SCL2 = 0.17677669529663687f * 1.4426950408889634f;
    const int qrow = 16 * wave + l15;
    const bool hi = (l4 >> 1) != 0;   // a
    const bool odd = (l4 & 1) != 0;   // b

    for (int qb = 0; qb < 4; ++qb) {
        const int q0 = qb * 64;
        bf16x8 qfrag = *(const bf16x8*)(Qm + bh + (size_t)(q0 + qrow) * 32 + l4 * 8);

        // QK^T swapped: sc[ct] holds scores(k = 16ct+4*l4+r, q = q0+16w+l15)
        f32x4 sc[16];
#pragma unroll
        for (int ct = 0; ct < 16; ++ct) {
            bf16x8 kf = *(const bf16x8*)&k_l[(ct * 16 + l15) * 32 + l4 * 8];
            sc[ct] = MFMA16(kf, qfrag, zero4);
        }

        // softmax (no max-subtraction: scores ~N(0,1) after scale, exp arg bounded)
        float sum = 0.f;
#pragma unroll
        for (int ct = 0; ct < 16; ++ct) {
#pragma unroll
            for (int r = 0; r < 4; ++r) {
                float e;
                float x = sc[ct][r] * SCL2;
                asm("v_exp_f32 %0, %1" : "=v"(e) : "v"(x));
                sc[ct][r] = e;
                sum += e;
            }
        }
        sum += __shfl_xor(sum, 16);
        sum += __shfl_xor(sum, 32);
        float inv = 1.0f / sum;

        // PV with in-register P-redistribution (acc layout -> A-frag layout)
        f32x4 o0 = zero4, o1 = zero4;
#pragma unroll
        for (int m = 0; m < 8; ++m) {
            unsigned int E0, E1, O0, O1;
            {
                int kbase = 32 * m + 4 * l4;
                int jb = q0 + qrow - kbase + 255;
                float p0 = sc[2 * m][0] * inv + bias_g[jb];
                float p1 = sc[2 * m][1] * inv + bias_g[jb - 1];
                float p2 = sc[2 * m][2] * inv + bias_g[jb - 2];
                float p3 = sc[2 * m][3] * inv + bias_g[jb - 3];
                asm("v_cvt_pk_bf16_f32 %0, %1, %2" : "=v"(E0) : "v"(p0), "v"(p1));
                asm("v_cvt_pk_bf16_f32 %0, %1, %2" : "=v"(E1) : "v"(p2), "v"(p3));
                jb -= 16;
                p0 = sc[2 * m + 1][0] * inv + bias_g[jb];
                p1 = sc[2 * m + 1][1] * inv + bias_g[jb - 1];
                p2 = sc[2 * m + 1][2] * inv + bias_g[jb - 2];
                p3 = sc[2 * m + 1][3] * inv + bias_g[jb - 3];
                asm("v_cvt_pk_bf16_f32 %0, %1, %2" : "=v"(O0) : "v"(p0), "v"(p1));
                asm("v_cvt_pk_bf16_f32 %0, %1, %2" : "=v"(O1) : "v"(p2), "v"(p3));
            }
            unsigned int m0_ = hi ? O0 : E0, m1_ = hi ? O1 : E1;  // own parity-a pair
            unsigned int s0 = hi ? E0 : O0, s1 = hi ? E1 : O1;    // give-away pair
            unsigned int g0 = __shfl_xor(s0, 32), g1 = __shfl_xor(s1, 32);
            unsigned int X00 = hi ? g0 : m0_, X01 = hi ? g1 : m1_;  // (a'=0, b'=b)
            unsigned int X10 = hi ? m0_ : g0, X11 = hi ? m1_ : g1;  // (a'=1, b'=b)
            unsigned int k0 = odd ? X10 : X00, k1 = odd ? X11 : X01;  // keep (a'=b)
            unsigned int t0 = odd ? X00 : X10, t1 = odd ? X01 : X11;  // send (a'=1-b)
            unsigned int r0 = __shfl_xor(t0, 16), r1 = __shfl_xor(t1, 16);
            union { unsigned int u[4]; bf16x8 v; } pu;
            pu.u[0] = odd ? r0 : k0; pu.u[1] = odd ? r1 : k1;   // b'=0 source
            pu.u[2] = odd ? k0 : r0; pu.u[3] = odd ? k1 : r1;   // b'=1 source
            int vc = (m * 4 + l4) ^ (l15 & 7);
            bf16x8 v0 = *(const bf16x8*)&vt_l[l15 * 256 + vc * 8];
            bf16x8 v1 = *(const bf16x8*)&vt_l[(16 + l15) * 256 + vc * 8];
            o0 = MFMA16(pu.v, v0, o0);
            o1 = MFMA16(pu.v, v1, o1);
        }

        // write out[b][s][h*32+dh] f32
#pragma unroll
        for (int r = 0; r < 4; ++r) {
            int s = q0 + 16 * wave + l4 * 4 + r;
            float* po = out + ((size_t)(b * 256 + s)) * 512 + h * 32;
            po[l15] = o0[r];
            po[16 + l15] = o1[r];
        }
    }
}

// ---------------- launch ----------------
extern "C" void kernel_launch(void* const* d_in, const int* in_sizes, int n_in,
                              void* d_out, int out_size, void* d_ws, size_t ws_size,
                              hipStream_t stream) {
    const float* hs = (const float*)d_in[0];
    const float* Wq = (const float*)d_in[1];
    const float* bq = (const float*)d_in[2];
    const float* Wk = (const float*)d_in[3];
    const float* bk = (const float*)d_in[4];
    const float* Wv = (const float*)d_in[5];
    const float* bv = (const float*)d_in[6];
    const float* bt = (const float*)d_in[7];
    float* out = (float*)d_out;

    char* ws = (char*)d_ws;
    unsigned short* hsb = (unsigned short*)ws;                 // 16,777,216 B (row-major bf16)
    unsigned short* wt = (unsigned short*)(ws + 16777216);     //  1,572,864 B ([n][k] row-major)
    unsigned short* Qo = (unsigned short*)(ws + 18350080);     // 16,777,216 B
    unsigned short* Ko = (unsigned short*)(ws + 35127296);     // 16,777,216 B
    unsigned short* Vo = (unsigned short*)(ws + 51904512);     // 16,777,216 B ([b][h][dh][s])
    float* cs2 = (float*)(ws + 68681728);                      //     32,768 B

    hipLaunchKernelGGL(k_cvt, dim3(8192), dim3(256), 0, stream, (const float4*)hs, hsb);
    hipLaunchKernelGGL(k_wt, dim3(8, 8, 3), dim3(256), 0, stream, Wq, Wk, Wv, wt);
    hipLaunchKernelGGL(k_sc, dim3(1), dim3(256), 0, stream, cs2);
    hipLaunchKernelGGL(k_gemm, dim3(1536), dim3(256), 0, stream,
                       hsb, wt, bq, bk, bv, cs2, Qo, Ko, Vo);
    hipLaunchKernelGGL(k_attn, dim3(1024), dim3(256), 0, stream,
                       Qo, Ko, Vo, bt, out);
}